// Round 4
// baseline (55.253 us; speedup 1.0000x reference)
//
#include <hip/hip_runtime.h>
#include <math.h>

#define B 64
#define S 300
#define R 100
#define F 10
#define RF (R * F)
#define TPW 3                  // tiles (s values) per wave
#define WPB 4                  // waves per block
#define SPB (TPW * WPB)        // 12 s per block
#define BPB (S / SPB)          // 25 blocks per b
#define NBLK (B * BPB)         // 1600 blocks

typedef float v2 __attribute__((ext_vector_type(2)));

__device__ __forceinline__ v2 vsplat(float s) { v2 r; r.x = s; r.y = s; return r; }
__device__ __forceinline__ v2 fma2(v2 a, float b, v2 c) {
    return __builtin_elementwise_fma(a, vsplat(b), c);
}
__device__ __forceinline__ v2 vmax2(v2 a, v2 b) { return __builtin_elementwise_max(a, b); }
// elu(x) = max(x, exp(min(x,0)) - 1)
__device__ __forceinline__ v2 elu2(v2 x) {
    v2 xm = __builtin_elementwise_min(x, vsplat(0.f));
    v2 e; e.x = __expf(xm.x); e.y = __expf(xm.y);
    return __builtin_elementwise_max(x, e - vsplat(1.f));
}

// one DPP-shifted add step; invalid/unwritten lanes contribute 0
template <int CTRL>
__device__ __forceinline__ float dppadd(float v) {
    int t = __builtin_amdgcn_update_dpp(0, __float_as_int(v), CTRL, 0xF, 0xF, true);
    return v + __int_as_float(t);
}
// full-wave64 sum -> SGPR (row_shr 1/2/4/8, row_bcast 15/31, readlane 63)
__device__ __forceinline__ float wsum_dpp(float v) {
    v = dppadd<0x111>(v);
    v = dppadd<0x112>(v);
    v = dppadd<0x114>(v);
    v = dppadd<0x118>(v);
    v = dppadd<0x142>(v);
    v = dppadd<0x143>(v);
    return __uint_as_float(__builtin_amdgcn_readlane(__float_as_uint(v), 63));
}
__device__ __forceinline__ float rdlane0(float v) {
    return __uint_as_float(__builtin_amdgcn_readlane(__float_as_uint(v), 0));
}
__device__ __forceinline__ unsigned int fkey(float f) {
    unsigned int bits = __float_as_uint(f);
    return (bits & 0x80000000u) ? ~bits : (bits | 0x80000000u);
}

struct Feats { v2 f[F]; };

__device__ __forceinline__ void load_tile(const float* __restrict__ xt,
                                          int r1, int r2, Feats& ft) {
    const float2* p1 = (const float2*)(xt + r1 * F);
    const float2* p2 = (const float2*)(xt + r2 * F);
#pragma unroll
    for (int i = 0; i < F; i += 2) {
        float2 u1 = p1[i >> 1];
        float2 u2 = p2[i >> 1];
        ft.f[i].x = u1.x;     ft.f[i].y = u2.x;
        ft.f[i + 1].x = u1.y; ft.f[i + 1].y = u2.y;
    }
}

__device__ __forceinline__ v2 tile_compute(
    const Feats& ft, bool a2,
    const float* __restrict__ l1_w, const float* __restrict__ l1_b,
    const float* __restrict__ l2_w, const float* __restrict__ l2_b,
    const float* __restrict__ l3_w, const float* __restrict__ l3_b,
    const float* __restrict__ fc1_w, const float* __restrict__ fc1_b,
    const float* __restrict__ fc2_w, const float* __restrict__ fc2_b,
    const float* __restrict__ fc3_w, const float* __restrict__ fc3_b)
{
    const v2* f = ft.f;
    // read-0 feats -> SGPR
    const float x00 = rdlane0(f[0].x);
    const float x01 = rdlane0(f[1].x);
    const float x02 = rdlane0(f[2].x);
    const float x03 = rdlane0(f[3].x);
    v2 rdot = fma2(f[0], x00, fma2(f[1], x01, fma2(f[2], x02, f[3] * vsplat(x03))));

    // mean of feat[0:4] over 100 reads (DPP, result uniform in SGPR)
    float bm[4];
#pragma unroll
    for (int k = 0; k < 4; ++k) {
        float loc = f[k].x + (a2 ? f[k].y : 0.f);
        bm[k] = wsum_dpp(loc) * (1.f / R);
    }

    // l1: [bm(4), rdot, f(10)]
    float pre1[5];
#pragma unroll
    for (int o = 0; o < 5; ++o) {
        float acc = l1_b[o];
#pragma unroll
        for (int k = 0; k < 4; ++k) acc = fmaf(bm[k], l1_w[o * 15 + k], acc);
        pre1[o] = acc;
    }
    v2 y1[5];
#pragma unroll
    for (int o = 0; o < 5; ++o) {
        v2 acc = vsplat(pre1[o]);
        acc = fma2(rdot, l1_w[o * 15 + 4], acc);
#pragma unroll
        for (int k = 0; k < F; ++k) acc = fma2(f[k], l1_w[o * 15 + 5 + k], acc);
        y1[o] = elu2(acc);
    }
    v2 y2[5];
#pragma unroll
    for (int o = 0; o < 5; ++o) {
        v2 acc = vsplat(l2_b[o]) + y1[o];
#pragma unroll
        for (int k = 0; k < 5; ++k) acc = fma2(y1[k], l2_w[o * 5 + k], acc);
        y2[o] = elu2(acc);
    }
    v2 y3[5];
#pragma unroll
    for (int o = 0; o < 5; ++o) {
        v2 acc = vsplat(l3_b[o]) + y2[o];
#pragma unroll
        for (int k = 0; k < 5; ++k) acc = fma2(y2[k], l3_w[o * 5 + k], acc);
        y3[o] = elu2(acc);
    }

    // mean of y3 over 100 reads
    float ym[5];
#pragma unroll
    for (int k = 0; k < 5; ++k) {
        float loc = y3[k].x + (a2 ? y3[k].y : 0.f);
        ym[k] = wsum_dpp(loc) * (1.f / R);
    }

    // fc1: [ym(5), bm(4), rdot, f(10)]
    float pre2[5];
#pragma unroll
    for (int o = 0; o < 5; ++o) {
        float acc = fc1_b[o];
#pragma unroll
        for (int k = 0; k < 5; ++k) acc = fmaf(ym[k], fc1_w[o * 20 + k], acc);
#pragma unroll
        for (int k = 0; k < 4; ++k) acc = fmaf(bm[k], fc1_w[o * 20 + 5 + k], acc);
        pre2[o] = acc;
    }
    v2 h1[5];
#pragma unroll
    for (int o = 0; o < 5; ++o) {
        v2 acc = vsplat(pre2[o]);
        acc = fma2(rdot, fc1_w[o * 20 + 9], acc);
#pragma unroll
        for (int k = 0; k < F; ++k) acc = fma2(f[k], fc1_w[o * 20 + 10 + k], acc);
        h1[o] = elu2(acc);
    }
    v2 h2[5];
#pragma unroll
    for (int o = 0; o < 5; ++o) {
        v2 acc = vsplat(fc2_b[o]) + h1[o];
#pragma unroll
        for (int k = 0; k < 5; ++k) acc = fma2(h1[k], fc2_w[o * 5 + k], acc);
        h2[o] = elu2(acc);
    }
    // fc3 raw accumulator (sigmoid(5*elu(.)) monotone -> max commutes)
    v2 hacc = vsplat(fc3_b[0]);
#pragma unroll
    for (int k = 0; k < 5; ++k) hacc = fma2(h2[k], fc3_w[k], hacc);
    return hacc;
}

__global__ __launch_bounds__(256) void alt_pred_k1(
    const float* __restrict__ x,
    const float* __restrict__ l1_w, const float* __restrict__ l1_b,
    const float* __restrict__ l2_w, const float* __restrict__ l2_b,
    const float* __restrict__ l3_w, const float* __restrict__ l3_b,
    const float* __restrict__ fc1_w, const float* __restrict__ fc1_b,
    const float* __restrict__ fc2_w, const float* __restrict__ fc2_b,
    const float* __restrict__ fc3_w, const float* __restrict__ fc3_b,
    unsigned int* __restrict__ wsmax)
{
    const int tid = threadIdx.x;
    const int wv = tid >> 6;
    const int lane = tid & 63;
    const int b = blockIdx.x / BPB;
    const int cb = blockIdx.x % BPB;
    const int s0 = cb * SPB + wv * TPW;
    const float* xw = x + ((size_t)b * S + s0) * RF;

    const bool a2 = (lane < R - 64);
    const int r2 = a2 ? (lane + 64) : (R - 1);

    // depth-1 prefetch across the wave's 3 tiles
    Feats f0, f1;
    load_tile(xw, lane, r2, f0);
    load_tile(xw + RF, lane, r2, f1);
    v2 m = tile_compute(f0, a2, l1_w, l1_b, l2_w, l2_b, l3_w, l3_b,
                        fc1_w, fc1_b, fc2_w, fc2_b, fc3_w, fc3_b);
    load_tile(xw + 2 * RF, lane, r2, f0);
    m = vmax2(m, tile_compute(f1, a2, l1_w, l1_b, l2_w, l2_b, l3_w, l3_b,
                              fc1_w, fc1_b, fc2_w, fc2_b, fc3_w, fc3_b));
    m = vmax2(m, tile_compute(f0, a2, l1_w, l1_b, l2_w, l2_b, l3_w, l3_b,
                              fc1_w, fc1_b, fc2_w, fc2_b, fc3_w, fc3_b));

    // block-level max combine (4 waves, same b) -> one atomic set per block
    __shared__ v2 red[WPB][64];
    red[wv][lane] = m;
    __syncthreads();
    if (wv == 0) {
        v2 mm = vmax2(vmax2(red[0][lane], red[1][lane]),
                      vmax2(red[2][lane], red[3][lane]));
        atomicMax(&wsmax[b * R + lane], fkey(mm.x));
        if (a2) atomicMax(&wsmax[b * R + lane + 64], fkey(mm.y));
    }
}

__global__ void alt_pred_k2(const unsigned int* __restrict__ wsmax,
                            float* __restrict__ out)
{
    const int i = blockIdx.x * blockDim.x + threadIdx.x;
    if (i < B * R) {
        const unsigned int key = wsmax[i];
        const unsigned int bits = (key & 0x80000000u) ? (key & 0x7FFFFFFFu) : ~key;
        const float acc = __uint_as_float(bits);
        const float h = 5.f * (acc > 0.f ? acc : (__expf(acc) - 1.f));
        out[i] = 1.f / (1.f + __expf(-h));
    }
}

extern "C" void kernel_launch(void* const* d_in, const int* in_sizes, int n_in,
                              void* d_out, int out_size, void* d_ws, size_t ws_size,
                              hipStream_t stream) {
    const float* x     = (const float*)d_in[0];
    const float* l1_w  = (const float*)d_in[1];
    const float* l1_b  = (const float*)d_in[2];
    const float* l2_w  = (const float*)d_in[3];
    const float* l2_b  = (const float*)d_in[4];
    const float* l3_w  = (const float*)d_in[5];
    const float* l3_b  = (const float*)d_in[6];
    const float* fc1_w = (const float*)d_in[7];
    const float* fc1_b = (const float*)d_in[8];
    const float* fc2_w = (const float*)d_in[9];
    const float* fc2_b = (const float*)d_in[10];
    const float* fc3_w = (const float*)d_in[11];
    const float* fc3_b = (const float*)d_in[12];

    unsigned int* wsmax = (unsigned int*)d_ws;
    hipMemsetAsync(d_ws, 0, (size_t)B * R * sizeof(unsigned int), stream);

    alt_pred_k1<<<NBLK, 256, 0, stream>>>(
        x, l1_w, l1_b, l2_w, l2_b, l3_w, l3_b,
        fc1_w, fc1_b, fc2_w, fc2_b, fc3_w, fc3_b, wsmax);

    alt_pred_k2<<<(B * R + 255) / 256, 256, 0, stream>>>(wsmax, (float*)d_out);
}

// Round 5
// 41.370 us; speedup vs baseline: 1.3356x; 1.3356x over previous
//
#include <hip/hip_runtime.h>
#include <math.h>

#define B 64
#define S 300
#define R 100
#define F 10
#define RF (R * F)
#define NTILE (B * S)          // 19200 tiles, 2 per wave
#define NWAVE (NTILE / 2)      // 9600 waves
#define NBLK (NWAVE / 4)       // 2400 blocks of 4 waves

typedef float v2 __attribute__((ext_vector_type(2)));
typedef float v4 __attribute__((ext_vector_type(4)));

__device__ __forceinline__ v4 splat4(float s) { v4 r; r.x = s; r.y = s; r.z = s; r.w = s; return r; }
// (a,a,b,b): per-tile uniform pair
__device__ __forceinline__ v4 hsplat(float a, float b) { v4 r; r.x = a; r.y = a; r.z = b; r.w = b; return r; }
__device__ __forceinline__ v4 fma4(v4 a, float b, v4 c) {
    return __builtin_elementwise_fma(a, splat4(b), c);
}
__device__ __forceinline__ v4 fma4v(v4 a, v4 b, v4 c) {
    return __builtin_elementwise_fma(a, b, c);
}
// elu(x) = max(x, exp(min(x,0)) - 1)
__device__ __forceinline__ v4 elu4(v4 x) {
    v4 xm = __builtin_elementwise_min(x, splat4(0.f));
    v4 e;
    e.x = __expf(xm.x); e.y = __expf(xm.y); e.z = __expf(xm.z); e.w = __expf(xm.w);
    return __builtin_elementwise_max(x, e - splat4(1.f));
}

// one DPP-shifted add step; out-of-row lanes contribute 0
template <int CTRL>
__device__ __forceinline__ float dppadd(float v) {
    int t = __builtin_amdgcn_update_dpp(0, __float_as_int(v), CTRL, 0xF, 0xF, true);
    return v + __int_as_float(t);
}
// full-wave64 sum -> uniform (row_shr 1/2/4/8, row_bcast 15/31, readlane 63)
__device__ __forceinline__ float wsum_dpp(float v) {
    v = dppadd<0x111>(v);
    v = dppadd<0x112>(v);
    v = dppadd<0x114>(v);
    v = dppadd<0x118>(v);
    v = dppadd<0x142>(v);
    v = dppadd<0x143>(v);
    return __uint_as_float(__builtin_amdgcn_readlane(__float_as_uint(v), 63));
}
__device__ __forceinline__ float rdlane0(float v) {
    return __uint_as_float(__builtin_amdgcn_readlane(__float_as_uint(v), 0));
}
__device__ __forceinline__ unsigned int fkey(float f) {
    unsigned int bits = __float_as_uint(f);
    return (bits & 0x80000000u) ? ~bits : (bits | 0x80000000u);
}

__global__ __launch_bounds__(256) void alt_pred_k1(
    const float* __restrict__ x,
    const float* __restrict__ l1_w, const float* __restrict__ l1_b,
    const float* __restrict__ l2_w, const float* __restrict__ l2_b,
    const float* __restrict__ l3_w, const float* __restrict__ l3_b,
    const float* __restrict__ fc1_w, const float* __restrict__ fc1_b,
    const float* __restrict__ fc2_w, const float* __restrict__ fc2_b,
    const float* __restrict__ fc3_w, const float* __restrict__ fc3_b,
    unsigned int* __restrict__ wsmax)
{
    const int tid = threadIdx.x;
    const int wv = tid >> 6;
    const int lane = tid & 63;
    const int gw = blockIdx.x * 4 + wv;     // global wave id
    const int t0 = gw * 2;                  // even tile; pair never straddles b
    const int b = t0 / S;
    const float* xA = x + (size_t)t0 * RF;
    const float* xB = xA + RF;

    const bool a2 = (lane < R - 64);
    const int r2 = a2 ? (lane + 64) : (R - 1);

    // ---- load 2 tiles x 2 reads, packed as (A.r1, A.r2, B.r1, B.r2) ----
    v4 f[F];
    {
        const float2* pA1 = (const float2*)(xA + lane * F);
        const float2* pA2 = (const float2*)(xA + r2 * F);
        const float2* pB1 = (const float2*)(xB + lane * F);
        const float2* pB2 = (const float2*)(xB + r2 * F);
#pragma unroll
        for (int i = 0; i < F; i += 2) {
            float2 a1 = pA1[i >> 1], a2v = pA2[i >> 1];
            float2 b1 = pB1[i >> 1], b2v = pB2[i >> 1];
            f[i].x = a1.x;     f[i].y = a2v.x; f[i].z = b1.x;     f[i].w = b2v.x;
            f[i + 1].x = a1.y; f[i + 1].y = a2v.y; f[i + 1].z = b1.y; f[i + 1].w = b2v.y;
        }
    }

    // ---- read-0 feats per tile -> uniform ----
    float x0A[4], x0B[4];
#pragma unroll
    for (int k = 0; k < 4; ++k) {
        x0A[k] = rdlane0(f[k].x);
        x0B[k] = rdlane0(f[k].z);
    }
    v4 rdot = f[3] * hsplat(x0A[3], x0B[3]);
    rdot = fma4v(f[2], hsplat(x0A[2], x0B[2]), rdot);
    rdot = fma4v(f[1], hsplat(x0A[1], x0B[1]), rdot);
    rdot = fma4v(f[0], hsplat(x0A[0], x0B[0]), rdot);

    // ---- mean of feat[0:4] over 100 reads, per tile (8 concurrent DPP trees) ----
    float bmA[4], bmB[4];
#pragma unroll
    for (int k = 0; k < 4; ++k) {
        float locA = f[k].x + (a2 ? f[k].y : 0.f);
        float locB = f[k].z + (a2 ? f[k].w : 0.f);
        bmA[k] = wsum_dpp(locA) * (1.f / R);
        bmB[k] = wsum_dpp(locB) * (1.f / R);
    }

    // ---- l1: [bm(4), rdot, f(10)] ----
    v4 y1[5];
#pragma unroll
    for (int o = 0; o < 5; ++o) {
        float pA = l1_b[o], pB = l1_b[o];
#pragma unroll
        for (int k = 0; k < 4; ++k) {
            pA = fmaf(bmA[k], l1_w[o * 15 + k], pA);
            pB = fmaf(bmB[k], l1_w[o * 15 + k], pB);
        }
        v4 acc = hsplat(pA, pB);
        acc = fma4(rdot, l1_w[o * 15 + 4], acc);
#pragma unroll
        for (int k = 0; k < F; ++k) acc = fma4(f[k], l1_w[o * 15 + 5 + k], acc);
        y1[o] = elu4(acc);
    }
    // ---- l2 (+residual) ----
    v4 y2[5];
#pragma unroll
    for (int o = 0; o < 5; ++o) {
        v4 acc = splat4(l2_b[o]) + y1[o];
#pragma unroll
        for (int k = 0; k < 5; ++k) acc = fma4(y1[k], l2_w[o * 5 + k], acc);
        y2[o] = elu4(acc);
    }
    // ---- l3 (+residual) ----
    v4 y3[5];
#pragma unroll
    for (int o = 0; o < 5; ++o) {
        v4 acc = splat4(l3_b[o]) + y2[o];
#pragma unroll
        for (int k = 0; k < 5; ++k) acc = fma4(y2[k], l3_w[o * 5 + k], acc);
        y3[o] = elu4(acc);
    }

    // ---- mean of y3 over 100 reads, per tile (10 concurrent DPP trees) ----
    float ymA[5], ymB[5];
#pragma unroll
    for (int k = 0; k < 5; ++k) {
        float locA = y3[k].x + (a2 ? y3[k].y : 0.f);
        float locB = y3[k].z + (a2 ? y3[k].w : 0.f);
        ymA[k] = wsum_dpp(locA) * (1.f / R);
        ymB[k] = wsum_dpp(locB) * (1.f / R);
    }

    // ---- fc1: [ym(5), bm(4), rdot, f(10)] ----
    v4 h1[5];
#pragma unroll
    for (int o = 0; o < 5; ++o) {
        float pA = fc1_b[o], pB = fc1_b[o];
#pragma unroll
        for (int k = 0; k < 5; ++k) {
            pA = fmaf(ymA[k], fc1_w[o * 20 + k], pA);
            pB = fmaf(ymB[k], fc1_w[o * 20 + k], pB);
        }
#pragma unroll
        for (int k = 0; k < 4; ++k) {
            pA = fmaf(bmA[k], fc1_w[o * 20 + 5 + k], pA);
            pB = fmaf(bmB[k], fc1_w[o * 20 + 5 + k], pB);
        }
        v4 acc = hsplat(pA, pB);
        acc = fma4(rdot, fc1_w[o * 20 + 9], acc);
#pragma unroll
        for (int k = 0; k < F; ++k) acc = fma4(f[k], fc1_w[o * 20 + 10 + k], acc);
        h1[o] = elu4(acc);
    }
    // ---- fc2 (+residual) ----
    v4 h2[5];
#pragma unroll
    for (int o = 0; o < 5; ++o) {
        v4 acc = splat4(fc2_b[o]) + h1[o];
#pragma unroll
        for (int k = 0; k < 5; ++k) acc = fma4(h1[k], fc2_w[o * 5 + k], acc);
        h2[o] = elu4(acc);
    }
    // ---- fc3 raw accumulator (sigmoid(5*elu(.)) monotone -> max commutes) ----
    v4 hacc = splat4(fc3_b[0]);
#pragma unroll
    for (int k = 0; k < 5; ++k) hacc = fma4(h2[k], fc3_w[k], hacc);

    // pair-max over the wave's 2 tiles (same b), then one atomic per read slot
    const float m1 = fmaxf(hacc.x, hacc.z);   // read r1 = lane
    const float m2 = fmaxf(hacc.y, hacc.w);   // read r2 = lane+64
    atomicMax(&wsmax[b * R + lane], fkey(m1));
    if (a2) atomicMax(&wsmax[b * R + lane + 64], fkey(m2));
}

__global__ void alt_pred_k2(const unsigned int* __restrict__ wsmax,
                            float* __restrict__ out)
{
    const int i = blockIdx.x * blockDim.x + threadIdx.x;
    if (i < B * R) {
        const unsigned int key = wsmax[i];
        const unsigned int bits = (key & 0x80000000u) ? (key & 0x7FFFFFFFu) : ~key;
        const float acc = __uint_as_float(bits);
        const float h = 5.f * (acc > 0.f ? acc : (__expf(acc) - 1.f));
        out[i] = 1.f / (1.f + __expf(-h));
    }
}

extern "C" void kernel_launch(void* const* d_in, const int* in_sizes, int n_in,
                              void* d_out, int out_size, void* d_ws, size_t ws_size,
                              hipStream_t stream) {
    const float* x     = (const float*)d_in[0];
    const float* l1_w  = (const float*)d_in[1];
    const float* l1_b  = (const float*)d_in[2];
    const float* l2_w  = (const float*)d_in[3];
    const float* l2_b  = (const float*)d_in[4];
    const float* l3_w  = (const float*)d_in[5];
    const float* l3_b  = (const float*)d_in[6];
    const float* fc1_w = (const float*)d_in[7];
    const float* fc1_b = (const float*)d_in[8];
    const float* fc2_w = (const float*)d_in[9];
    const float* fc2_b = (const float*)d_in[10];
    const float* fc3_w = (const float*)d_in[11];
    const float* fc3_b = (const float*)d_in[12];

    unsigned int* wsmax = (unsigned int*)d_ws;
    hipMemsetAsync(d_ws, 0, (size_t)B * R * sizeof(unsigned int), stream);

    alt_pred_k1<<<NBLK, 256, 0, stream>>>(
        x, l1_w, l1_b, l2_w, l2_b, l3_w, l3_b,
        fc1_w, fc1_b, fc2_w, fc2_b, fc3_w, fc3_b, wsmax);

    alt_pred_k2<<<(B * R + 255) / 256, 256, 0, stream>>>(wsmax, (float*)d_out);
}